// Round 10
// baseline (150.737 us; speedup 1.0000x reference)
//
#include <hip/hip_runtime.h>
#include <cstddef>

#define Hn 1024
#define Vn 32000
#define Sn 4096
#define CSHIFT 20.0f

__device__ __forceinline__ float wave_reduce_sum(float v) {
#pragma unroll
    for (int o = 32; o > 0; o >>= 1) v += __shfl_down(v, o, 64);
    return v;
}

// producer/consumer ordering within one dispatch (agent scope: XCD-safe)
__device__ __forceinline__ void block_signal(int* cnt, int t) {
    __threadfence();                 // every thread's writes -> agent visible
    __syncthreads();                 // all threads fenced before the count
    if (t == 0) __hip_atomic_fetch_add(cnt, 1, __ATOMIC_RELEASE, __HIP_MEMORY_SCOPE_AGENT);
}
__device__ __forceinline__ void block_wait(const int* cnt, int target, int t) {
    if (t == 0) {
        while (__hip_atomic_load(cnt, __ATOMIC_ACQUIRE, __HIP_MEMORY_SCOPE_AGENT) < target)
            __builtin_amdgcn_s_sleep(4);
    }
    __syncthreads();
    __threadfence();
}

// ws layout (floats):
// [0,1024)      h
// [1024,2048)   raw ctx (unnormalized, atomic target, zeroed by k_gru blk0)
// [2048,3072)   v = attn_w^T h
// [3072,7168)   escore (e^(s-CSHIFT))
// [7168]        denom (atomic target)
// [7176..7178)  int counters: attnv_done, sctx_done

// ---------------- D1: GRU cell -> h (1024 blocks, block per output) ----------------
__global__ __launch_bounds__(256) void k_gru(const int* __restrict__ word,
                                             const float* __restrict__ emb,
                                             const float* __restrict__ h0,
                                             const float* __restrict__ w_ih,
                                             const float* __restrict__ w_hh,
                                             const float* __restrict__ b_ih,
                                             const float* __restrict__ b_hh,
                                             float* __restrict__ ws_h,
                                             float* __restrict__ ws_ctx,
                                             float* __restrict__ ws_denom,
                                             int*   __restrict__ ws_cnt,
                                             float* __restrict__ out_h)
{
    const int k = blockIdx.x;
    const int t = threadIdx.x;

    if (k == 0) {                       // zero atomic targets for this call
#pragma unroll
        for (int i = 0; i < 4; ++i) ws_ctx[t + i * 256] = 0.f;
        if (t == 0) { ws_denom[0] = 0.f; ws_cnt[0] = 0; ws_cnt[1] = 0; }
    }

    const float* x = emb + (size_t)word[0] * Hn;
    const float4 xv = ((const float4*)x)[t];
    const float4 hv = ((const float4*)h0)[t];

    float acc[6];
    const float* rows[6] = {
        w_ih + (size_t)k * Hn, w_ih + (size_t)(k + Hn) * Hn, w_ih + (size_t)(k + 2 * Hn) * Hn,
        w_hh + (size_t)k * Hn, w_hh + (size_t)(k + Hn) * Hn, w_hh + (size_t)(k + 2 * Hn) * Hn
    };
#pragma unroll
    for (int g = 0; g < 6; ++g) {
        const float4 w = ((const float4*)rows[g])[t];
        const float4 vv = (g < 3) ? xv : hv;
        acc[g] = w.x * vv.x + w.y * vv.y + w.z * vv.z + w.w * vv.w;
    }

    __shared__ float red[6][4];
    const int wv = t >> 6, lane = t & 63;
#pragma unroll
    for (int g = 0; g < 6; ++g) {
        const float s = wave_reduce_sum(acc[g]);
        if (lane == 0) red[g][wv] = s;
    }
    __syncthreads();
    if (t == 0) {
        float g0 = red[0][0] + red[0][1] + red[0][2] + red[0][3] + b_ih[k];
        float g1 = red[1][0] + red[1][1] + red[1][2] + red[1][3] + b_ih[k + Hn];
        float g2 = red[2][0] + red[2][1] + red[2][2] + red[2][3] + b_ih[k + 2 * Hn];
        float g3 = red[3][0] + red[3][1] + red[3][2] + red[3][3] + b_hh[k];
        float g4 = red[4][0] + red[4][1] + red[4][2] + red[4][3] + b_hh[k + Hn];
        float g5 = red[5][0] + red[5][1] + red[5][2] + red[5][3] + b_hh[k + 2 * Hn];
        float r = 1.f / (1.f + expf(-(g0 + g3)));
        float z = 1.f / (1.f + expf(-(g1 + g4)));
        float n = tanhf(g2 + r * g5);
        float hk = (1.f - z) * n + z * h0[k];
        ws_h[k]  = hk;
        out_h[k] = hk;
    }
}

// ---------------- D2: attnv | sctx | attn-out | h-half GEMV (one dispatch) ----------------
__global__ __launch_bounds__(256) void k_mid(const float* __restrict__ attn_w,
                                             const float* __restrict__ enc,
                                             const float* __restrict__ ws_h,
                                             float* __restrict__ ws_v,
                                             float* __restrict__ escore,
                                             float* __restrict__ ctx,
                                             float* __restrict__ denom,
                                             int*   __restrict__ cnt,
                                             float* __restrict__ out_attn,
                                             const float* __restrict__ out_w,
                                             const float* __restrict__ out_b,
                                             float* __restrict__ out)
{
    __shared__ float smem[5128];         // union: attnv p[16][17] / sctx rows+vsh+esl / GEMV c[1024]
    const int t = threadIdx.x, bid = blockIdx.x;
    const int wv = t >> 6, lane = t & 63;

    if (bid < 64) {
        // ---- attnv: v = attn_w^T h, 16-col strip ----
        const int tj = t >> 4, tk = t & 15;
        const int k = bid * 16 + tk;
        float acc = 0.f;
        for (int j = tj; j < Hn; j += 16)
            acc += attn_w[(size_t)j * Hn + k] * ws_h[j];
        smem[tj * 17 + tk] = acc;
        __syncthreads();
        if (t < 16) {
            float s = 0.f;
#pragma unroll
            for (int j = 0; j < 16; ++j) s += smem[j * 17 + t];
            ws_v[bid * 16 + t] = s;
        }
        block_signal(&cnt[0], t);
    } else if (bid < 192) {
        // ---- fused scores + exp + ctx partial (32 rows per block) ----
        block_wait(&cnt[0], 64, t);
        float* rows = smem;              // [4][1024]
        float* vsh  = smem + 4096;       // [1024]
        float* esl  = smem + 5120;       // [4]
        const int s0 = (bid - 64) * 32;

        ((float4*)vsh)[t] = ((const float4*)ws_v)[t];

        float4 acc = make_float4(0.f, 0.f, 0.f, 0.f);
        float dsum = 0.f;

        for (int g = 0; g < 8; ++g) {
            __syncthreads();             // prev group fully consumed (also orders vsh on g=0)
            const float* erow = enc + (size_t)(s0 + g * 4) * Hn;
#pragma unroll
            for (int r = 0; r < 4; ++r)
                ((float4*)(rows + r * Hn))[t] = ((const float4*)(erow + (size_t)r * Hn))[t];
            __syncthreads();

            float a = 0.f;
#pragma unroll
            for (int k = 0; k < 4; ++k) {
                const int idx = k * 256 + lane * 4;
                const float4 e = *(const float4*)(rows + wv * Hn + idx);
                a += e.x * vsh[idx] + e.y * vsh[idx + 1] + e.z * vsh[idx + 2] + e.w * vsh[idx + 3];
            }
            a = wave_reduce_sum(a);
            if (lane == 0) {
                const float ev = expf(a - CSHIFT);
                esl[wv] = ev;
                escore[s0 + g * 4 + wv] = ev;
            }
            __syncthreads();

            const float e0 = esl[0], e1 = esl[1], e2 = esl[2], e3 = esl[3];
            dsum += e0 + e1 + e2 + e3;
            const float4 r0 = ((const float4*)(rows))[t];
            const float4 r1 = ((const float4*)(rows + Hn))[t];
            const float4 r2 = ((const float4*)(rows + 2 * Hn))[t];
            const float4 r3 = ((const float4*)(rows + 3 * Hn))[t];
            acc.x += e0 * r0.x + e1 * r1.x + e2 * r2.x + e3 * r3.x;
            acc.y += e0 * r0.y + e1 * r1.y + e2 * r2.y + e3 * r3.y;
            acc.z += e0 * r0.z + e1 * r1.z + e2 * r2.z + e3 * r3.z;
            acc.w += e0 * r0.w + e1 * r1.w + e2 * r2.w + e3 * r3.w;
        }
        atomicAdd(&ctx[t * 4],     acc.x);
        atomicAdd(&ctx[t * 4 + 1], acc.y);
        atomicAdd(&ctx[t * 4 + 2], acc.z);
        atomicAdd(&ctx[t * 4 + 3], acc.w);
        if (t == 0) atomicAdd(denom, dsum);
        block_signal(&cnt[1], t);
    } else if (bid < 196) {
        // ---- attention output: normalize escore ----
        block_wait(&cnt[1], 128, t);
        const float inv = 1.f / denom[0];
        const int s = (bid - 192) * 1024 + t * 4;
        const float4 e = *(const float4*)(escore + s);
        *(float4*)(out_attn + s) = make_float4(e.x * inv, e.y * inv, e.z * inv, e.w * inv);
    } else {
        // ---- h-half GEMV: out[row] = out_w[row,0:1024].h + out_b[row] ----
        float* c = smem;
        ((float4*)c)[t] = ((const float4*)ws_h)[t];
        __syncthreads();
        const int row = (bid - 196) * 4 + wv;
        const float* w = out_w + (size_t)row * (2 * Hn);
        float acc = 0.f;
#pragma unroll
        for (int k = 0; k < 4; ++k) {
            const int idx = k * 256 + lane * 4;
            const float4 w4 = *(const float4*)(w + idx);
            acc += w4.x * c[idx] + w4.y * c[idx + 1] + w4.z * c[idx + 2] + w4.w * c[idx + 3];
        }
        acc = wave_reduce_sum(acc);
        if (lane == 0) out[row] = acc + out_b[row];
    }
}

// ---------------- D3: out[row] += (out_w[row,1024:2048] . rawctx) / denom ----------------
__global__ __launch_bounds__(256) void k_tail(const float* __restrict__ out_w,
                                              const float* __restrict__ ws_ctx,
                                              const float* __restrict__ denom,
                                              float* __restrict__ out)
{
    __shared__ float c[Hn];
    const int t = threadIdx.x;
    const float inv = 1.f / denom[0];
    ((float4*)c)[t] = ((const float4*)ws_ctx)[t];
    __syncthreads();
    const int wv = t >> 6, lane = t & 63;
    const int row = blockIdx.x * 4 + wv;
    const float* w = out_w + (size_t)row * (2 * Hn) + Hn;
    float acc = 0.f;
#pragma unroll
    for (int k = 0; k < 4; ++k) {
        const int idx = k * 256 + lane * 4;
        const float4 w4 = *(const float4*)(w + idx);
        acc += w4.x * c[idx] + w4.y * c[idx + 1] + w4.z * c[idx + 2] + w4.w * c[idx + 3];
    }
    acc = wave_reduce_sum(acc);
    if (lane == 0) out[row] += acc * inv;
}

extern "C" void kernel_launch(void* const* d_in, const int* in_sizes, int n_in,
                              void* d_out, int out_size, void* d_ws, size_t ws_size,
                              hipStream_t stream) {
    const int*   word   = (const int*)d_in[0];
    const float* h_last = (const float*)d_in[1];
    const float* enc    = (const float*)d_in[2];
    const float* emb    = (const float*)d_in[3];
    const float* w_ih   = (const float*)d_in[4];
    const float* w_hh   = (const float*)d_in[5];
    const float* b_ih   = (const float*)d_in[6];
    const float* b_hh   = (const float*)d_in[7];
    const float* attn_w = (const float*)d_in[8];
    /* d_in[9] attn_b: unused — uniform shift, softmax-invariant */
    const float* out_w  = (const float*)d_in[10];
    const float* out_b  = (const float*)d_in[11];
    float* out = (float*)d_out;
    float* ws  = (float*)d_ws;

    float* ws_h      = ws;          // 1024
    float* ws_ctx    = ws + 1024;   // 1024 raw ctx (atomic)
    float* ws_v      = ws + 2048;   // 1024
    float* ws_escore = ws + 3072;   // 4096
    float* ws_denom  = ws + 7168;   // 1
    int*   ws_cnt    = (int*)(ws + 7176); // 2 ints
    float* out_h     = out + Vn;
    float* out_attn  = out + Vn + Hn;

    k_gru<<<Hn, 256, 0, stream>>>(word, emb, h_last, w_ih, w_hh, b_ih, b_hh,
                                  ws_h, ws_ctx, ws_denom, ws_cnt, out_h);
    k_mid<<<196 + Vn / 4, 256, 0, stream>>>(attn_w, enc, ws_h, ws_v, ws_escore, ws_ctx,
                                            ws_denom, ws_cnt, out_attn, out_w, out_b, out);
    k_tail<<<Vn / 4, 256, 0, stream>>>(out_w, ws_ctx, ws_denom, out);
}

// Round 11
// 84.585 us; speedup vs baseline: 1.7821x; 1.7821x over previous
//
#include <hip/hip_runtime.h>
#include <cstddef>

#define Hn 1024
#define Vn 32000
#define Sn 4096
#define CSHIFT 20.0f

__device__ __forceinline__ float wave_reduce_sum(float v) {
#pragma unroll
    for (int o = 32; o > 0; o >>= 1) v += __shfl_down(v, o, 64);
    return v;
}

// ws layout (floats):
// [0,1024)      h
// [1024,2048)   raw ctx (unnormalized, atomic, zeroed by k_gru blk0)
// [2048,3072)   v = attn_w^T h (atomic, zeroed by k_gru blk0)
// [3072,7168)   escore (e^(s-CSHIFT))
// [7168]        denom (atomic, zeroed by k_gru blk0)

// out-head h-half: out[row] = out_w[row,0:1024].h + out_b[row]  (4 rows/block)
__device__ __forceinline__ void out_h_rows(const float* __restrict__ out_w,
                                           const float* __restrict__ out_b,
                                           const float* __restrict__ ws_h,
                                           float* __restrict__ out,
                                           float* __restrict__ c,   // 1024-float LDS
                                           int row_base, int t)
{
    ((float4*)c)[t] = ((const float4*)ws_h)[t];
    __syncthreads();
    const int wv = t >> 6, lane = t & 63;
    const int row = row_base + wv;
    const float* w = out_w + (size_t)row * (2 * Hn);
    float acc = 0.f;
#pragma unroll
    for (int k = 0; k < 4; ++k) {
        const int idx = k * 256 + lane * 4;
        const float4 w4 = *(const float4*)(w + idx);
        acc += w4.x * c[idx] + w4.y * c[idx + 1] + w4.z * c[idx + 2] + w4.w * c[idx + 3];
    }
    acc = wave_reduce_sum(acc);
    if (lane == 0) out[row] = acc + out_b[row];
}

// ---------------- D1: GRU cell -> h (1024 blocks, block per output) ----------------
__global__ __launch_bounds__(256) void k_gru(const int* __restrict__ word,
                                             const float* __restrict__ emb,
                                             const float* __restrict__ h0,
                                             const float* __restrict__ w_ih,
                                             const float* __restrict__ w_hh,
                                             const float* __restrict__ b_ih,
                                             const float* __restrict__ b_hh,
                                             float* __restrict__ ws_h,
                                             float* __restrict__ ws_ctx,
                                             float* __restrict__ ws_v,
                                             float* __restrict__ ws_denom,
                                             float* __restrict__ out_h)
{
    const int k = blockIdx.x;
    const int t = threadIdx.x;

    if (k == 0) {                       // zero all atomic targets for this call
#pragma unroll
        for (int i = 0; i < 4; ++i) {
            ws_ctx[t + i * 256] = 0.f;
            ws_v[t + i * 256]   = 0.f;
        }
        if (t == 0) ws_denom[0] = 0.f;
    }

    const float* x = emb + (size_t)word[0] * Hn;
    const float4 xv = ((const float4*)x)[t];
    const float4 hv = ((const float4*)h0)[t];

    float acc[6];
    const float* rows[6] = {
        w_ih + (size_t)k * Hn, w_ih + (size_t)(k + Hn) * Hn, w_ih + (size_t)(k + 2 * Hn) * Hn,
        w_hh + (size_t)k * Hn, w_hh + (size_t)(k + Hn) * Hn, w_hh + (size_t)(k + 2 * Hn) * Hn
    };
#pragma unroll
    for (int g = 0; g < 6; ++g) {
        const float4 w = ((const float4*)rows[g])[t];
        const float4 vv = (g < 3) ? xv : hv;
        acc[g] = w.x * vv.x + w.y * vv.y + w.z * vv.z + w.w * vv.w;
    }

    __shared__ float red[6][4];
    const int wv = t >> 6, lane = t & 63;
#pragma unroll
    for (int g = 0; g < 6; ++g) {
        const float s = wave_reduce_sum(acc[g]);
        if (lane == 0) red[g][wv] = s;
    }
    __syncthreads();
    if (t == 0) {
        float g0 = red[0][0] + red[0][1] + red[0][2] + red[0][3] + b_ih[k];
        float g1 = red[1][0] + red[1][1] + red[1][2] + red[1][3] + b_ih[k + Hn];
        float g2 = red[2][0] + red[2][1] + red[2][2] + red[2][3] + b_ih[k + 2 * Hn];
        float g3 = red[3][0] + red[3][1] + red[3][2] + red[3][3] + b_hh[k];
        float g4 = red[4][0] + red[4][1] + red[4][2] + red[4][3] + b_hh[k + Hn];
        float g5 = red[5][0] + red[5][1] + red[5][2] + red[5][3] + b_hh[k + 2 * Hn];
        float r = 1.f / (1.f + expf(-(g0 + g3)));
        float z = 1.f / (1.f + expf(-(g1 + g4)));
        float n = tanhf(g2 + r * g5);
        float hk = (1.f - z) * n + z * h0[k];
        ws_h[k]  = hk;
        out_h[k] = hk;
    }
}

// ------- D2: attnv-coalesced (blocks 0..127) ∥ h-half rows [0,23000) -------
__global__ __launch_bounds__(256) void k_a(const float* __restrict__ attn_w,
                                           const float* __restrict__ ws_h,
                                           float* __restrict__ v,
                                           const float* __restrict__ out_w,
                                           const float* __restrict__ out_b,
                                           float* __restrict__ out)
{
    __shared__ float c[Hn];
    const int t = threadIdx.x, bid = blockIdx.x;
    if (bid < 128) {
        // v[k] += sum_{j in block's 8 rows} attn_w[j][k] * h[j]  (rows coalesced)
        const int j0 = bid * 8;
        float4 acc = make_float4(0.f, 0.f, 0.f, 0.f);
#pragma unroll
        for (int r = 0; r < 8; ++r) {
            const int j = j0 + r;
            const float hj = ws_h[j];
            const float4 w4 = ((const float4*)(attn_w + (size_t)j * Hn))[t];
            acc.x += hj * w4.x; acc.y += hj * w4.y;
            acc.z += hj * w4.z; acc.w += hj * w4.w;
        }
        atomicAdd(&v[t * 4],     acc.x);
        atomicAdd(&v[t * 4 + 1], acc.y);
        atomicAdd(&v[t * 4 + 2], acc.z);
        atomicAdd(&v[t * 4 + 3], acc.w);
    } else {
        out_h_rows(out_w, out_b, ws_h, out, c, (bid - 128) * 4, t);
    }
}

// ------- D3: fused scores+exp+ctx (blocks 0..127, 32 rows each, ~4.2KB LDS)
//         ∥ h-half rows [23000,32000) -------
__global__ __launch_bounds__(256) void k_b(const float* __restrict__ enc,
                                           const float* __restrict__ ws_v,
                                           float* __restrict__ escore,
                                           float* __restrict__ ctx,
                                           float* __restrict__ denom,
                                           const float* __restrict__ ws_h,
                                           const float* __restrict__ out_w,
                                           const float* __restrict__ out_b,
                                           float* __restrict__ out)
{
    __shared__ float smem[Hn];
    __shared__ float esl[32];
    const int t = threadIdx.x, bid = blockIdx.x;
    if (bid < 128) {
        const int wv = t >> 6, lane = t & 63;
        const int s0 = bid * 32;

        ((float4*)smem)[t] = ((const float4*)ws_v)[t];   // v -> LDS
        __syncthreads();

        // scores: wave wv handles rows wv*8 .. wv*8+7
#pragma unroll
        for (int q = 0; q < 8; ++q) {
            const int r = wv * 8 + q;
            const float* row = enc + (size_t)(s0 + r) * Hn;
            float a = 0.f;
#pragma unroll
            for (int k = 0; k < 4; ++k) {
                const int idx = k * 256 + lane * 4;
                const float4 e = *(const float4*)(row + idx);
                a += e.x * smem[idx] + e.y * smem[idx + 1] + e.z * smem[idx + 2] + e.w * smem[idx + 3];
            }
            a = wave_reduce_sum(a);
            if (lane == 0) {
                const float ev = expf(a - CSHIFT);
                esl[r] = ev;
                escore[s0 + r] = ev;
            }
        }
        __syncthreads();

        // ctx partial: thread t owns cols 4t..4t+3; enc rows are L2-hot
        float4 acc = make_float4(0.f, 0.f, 0.f, 0.f);
#pragma unroll 4
        for (int s = 0; s < 32; ++s) {
            const float a = esl[s];
            const float4 e = ((const float4*)(enc + (size_t)(s0 + s) * Hn))[t];
            acc.x += a * e.x; acc.y += a * e.y; acc.z += a * e.z; acc.w += a * e.w;
        }
        atomicAdd(&ctx[t * 4],     acc.x);
        atomicAdd(&ctx[t * 4 + 1], acc.y);
        atomicAdd(&ctx[t * 4 + 2], acc.z);
        atomicAdd(&ctx[t * 4 + 3], acc.w);
        if (t == 0) {
            float d = 0.f;
#pragma unroll
            for (int s = 0; s < 32; ++s) d += esl[s];
            atomicAdd(denom, d);
        }
    } else {
        out_h_rows(out_w, out_b, ws_h, out, smem, 23000 + (bid - 128) * 4, t);
    }
}

// ------- D4: attn normalize (blocks 0..3) ∥ ctx-half GEMV (blocks 4..8003) -------
__global__ __launch_bounds__(256) void k_tail(const float* __restrict__ out_w,
                                              const float* __restrict__ ws_ctx,
                                              const float* __restrict__ escore,
                                              const float* __restrict__ denom,
                                              float* __restrict__ out_attn,
                                              float* __restrict__ out)
{
    __shared__ float c[Hn];
    const int t = threadIdx.x, bid = blockIdx.x;
    if (bid < 4) {
        const float inv = 1.f / denom[0];
        const int s = bid * 1024 + t * 4;
        const float4 e = *(const float4*)(escore + s);
        *(float4*)(out_attn + s) = make_float4(e.x * inv, e.y * inv, e.z * inv, e.w * inv);
    } else {
        const float inv = 1.f / denom[0];
        ((float4*)c)[t] = ((const float4*)ws_ctx)[t];
        __syncthreads();
        const int wv = t >> 6, lane = t & 63;
        const int row = (bid - 4) * 4 + wv;
        const float* w = out_w + (size_t)row * (2 * Hn) + Hn;
        float acc = 0.f;
#pragma unroll
        for (int k = 0; k < 4; ++k) {
            const int idx = k * 256 + lane * 4;
            const float4 w4 = *(const float4*)(w + idx);
            acc += w4.x * c[idx] + w4.y * c[idx + 1] + w4.z * c[idx + 2] + w4.w * c[idx + 3];
        }
        acc = wave_reduce_sum(acc);
        if (lane == 0) out[row] += acc * inv;
    }
}

extern "C" void kernel_launch(void* const* d_in, const int* in_sizes, int n_in,
                              void* d_out, int out_size, void* d_ws, size_t ws_size,
                              hipStream_t stream) {
    const int*   word   = (const int*)d_in[0];
    const float* h_last = (const float*)d_in[1];
    const float* enc    = (const float*)d_in[2];
    const float* emb    = (const float*)d_in[3];
    const float* w_ih   = (const float*)d_in[4];
    const float* w_hh   = (const float*)d_in[5];
    const float* b_ih   = (const float*)d_in[6];
    const float* b_hh   = (const float*)d_in[7];
    const float* attn_w = (const float*)d_in[8];
    /* d_in[9] attn_b: unused — uniform shift, softmax-invariant */
    const float* out_w  = (const float*)d_in[10];
    const float* out_b  = (const float*)d_in[11];
    float* out = (float*)d_out;
    float* ws  = (float*)d_ws;

    float* ws_h      = ws;          // 1024
    float* ws_ctx    = ws + 1024;   // 1024 raw ctx (atomic)
    float* ws_v      = ws + 2048;   // 1024 (atomic)
    float* ws_escore = ws + 3072;   // 4096
    float* ws_denom  = ws + 7168;   // 1
    float* out_h     = out + Vn;
    float* out_attn  = out + Vn + Hn;

    k_gru<<<Hn, 256, 0, stream>>>(word, emb, h_last, w_ih, w_hh, b_ih, b_hh,
                                  ws_h, ws_ctx, ws_v, ws_denom, out_h);
    k_a<<<128 + 5750, 256, 0, stream>>>(attn_w, ws_h, ws_v, out_w, out_b, out);
    k_b<<<128 + 2250, 256, 0, stream>>>(enc, ws_v, ws_escore, ws_ctx, ws_denom,
                                        ws_h, out_w, out_b, out);
    k_tail<<<4 + Vn / 4, 256, 0, stream>>>(out_w, ws_ctx, ws_escore, ws_denom,
                                           out_attn, out);
}